// Round 4
// baseline (139.485 us; speedup 1.0000x reference)
//
#include <hip/hip_runtime.h>

#define H   128
#define P   16             // points per TILE; 2 tiles (32 points) per block
#define NT  512            // 8 waves: grp = wave>>2 (tile), jquad = wave&3

typedef _Float16 v8h __attribute__((ext_vector_type(8)));
typedef __fp16   h2  __attribute__((ext_vector_type(2)));   // cvt_pkrtz return type
typedef float    v4f __attribute__((ext_vector_type(4)));
typedef float    v2f __attribute__((ext_vector_type(2)));   // -> VOP3P v_pk_*_f32

union PK4 { h2 h[4]; uint4 u; };       // 8 f16 = 16 B
union PK2 { h2 h[2]; uint2 u; };       // 4 f16 = 8 B

// State plane layout per tile: [pl][p][k], 128 f16 per row, XOR-octet swizzle;
// returns f16 index of octet o of row p within a tile's plane block.
__device__ __forceinline__ int soct(int pl, int p, int o) {
    return ((pl * P + p) * 16 + (o ^ (p & 15))) << 3;
}

// Prepass (free): Wt in MFMA A-fragment physical order ws[l][oct][j][8],
// oct = k>>3. Main kernel loads A fragments directly from this buffer into
// registers (64 KB, L2-resident) — A never touches LDS.
__global__ void wt_convert(const float* __restrict__ W1,
                           const float* __restrict__ W2,
                           _Float16* __restrict__ ws) {
    const int t = blockIdx.x * 64 + threadIdx.x;   // 0..16383 (u32 units)
    const int l = t >> 13;
    const int r = t & 8191;
    const int oct = r >> 9;
    const int rem = r & 511;
    const int j  = rem >> 2;
    const int wp = rem & 3;
    const int k  = oct * 8 + 2 * wp;
    const float* __restrict__ W = l ? W2 : W1;
    const float a = W[k * H + j];
    const float b = W[(k + 1) * H + j];
    union { h2 h; unsigned u; } q;
    q.h = __builtin_amdgcn_cvt_pkrtz(a, b);
    ((unsigned*)ws)[t] = q.u;
}

// Packed-pair tanh + derivatives: exp/rcp scalar, fma chain packed (VOP3P).
__device__ __forceinline__ v2f tanh_d2_p(v2f z, v2f& g1, v2f& g2) {
    v2f r;
    r.x = __builtin_amdgcn_rcpf(__expf(2.f * z.x) + 1.f);
    r.y = __builtin_amdgcn_rcpf(__expf(2.f * z.y) + 1.f);
    const v2f a = -2.f * r + 1.f;                  // e=inf -> r=0 -> a=1
    g1 = 1.f - a * a;
    g2 = -2.f * (a * g1);
    return a;
}

// R22: dual-tile staggered wave groups — attack the phase-lockstep floor.
// Evidence: R17 (72.3us), R21 (75.1us) structurally different, same dur; all
// pipes <50% (MFMA 29, VALU 47, LDS ~33); sum ~110% -> overlap would give
// ~35-45us. Co-resident blocks run identical barrier-quantized phases ->
// lockstep: at any instant the CU runs ONE pipe class. Fix: two independent
// 16-pt tiles per block, wave group 1 phase-shifted by one window, so every
// window issues GEMM (MFMA+LDS) AND elementwise (VALU/trans) concurrently:
//   W0 A:L0|B:-   W1 A:G1|B:L0   W2 A:E1|B:G1   W3 A:G2|B:E1
//   W4 A:E2p|B:G2  W5 A:red|B:E2p  W6 -|B:red
// Per-group phases = R21's proven code (group-private 24KB sS half).
// (512,4) => 128-VGPR cap (tiers are 8@<=64/4@<=128/2@<=256 — R19/R20 bug);
// live set ~95, 2 blocks/CU = 16 waves.
__global__ __launch_bounds__(NT, 4)
void pinn_hess_mfma(const float* __restrict__ X,
                    const float* __restrict__ W0, const float* __restrict__ b0,
                    const _Float16* __restrict__ Wt,
                    const float* __restrict__ b1, const float* __restrict__ b2,
                    const float* __restrict__ W3,
                    float* __restrict__ out, int N)
{
    __shared__ _Float16 sS[2 * 6 * P * H];    // 49152 B: two tile-private halves

    const int tid   = threadIdx.x;
    const int grp   = tid >> 8;               // 0/1 = tile group
    const int tl    = tid & 255;              // thread index within group
    const int jquad = (tid >> 6) & 3;         // group-local wave = j range /32
    const int lane  = tid & 63;
    const int quad  = lane >> 4;
    const int l15   = lane & 15;
    const int pbase = blockIdx.x * (2 * P) + grp * P;
    const int pmy   = l15;                    // this lane's point row (GEMM n)
    _Float16* sSg   = &sS[grp * (6 * P * H)];

    // A-fragment index (v8h units) for this lane: [oct = kc*4+quad][j][8]
    const int aoff = quad * H + jquad * 32 + l15;   // + kc*4*H, +16 for m-tile 1

    v4f C[6][2];

    // ---------------- phase bodies (group-local, R21-proven) ----------------
    auto L0 = [&]() {
        const int p = tl >> 4, o = tl & 15;
        const float x = X[2 * (pbase + p)];
        const float y = X[2 * (pbase + p) + 1];
        float wxv[8], wyv[8], bv[8];
        *(float4*)&wxv[0] = *(const float4*)&W0[o * 8];
        *(float4*)&wxv[4] = *(const float4*)&W0[o * 8 + 4];
        *(float4*)&wyv[0] = *(const float4*)&W0[H + o * 8];
        *(float4*)&wyv[4] = *(const float4*)&W0[H + o * 8 + 4];
        *(float4*)&bv[0]  = *(const float4*)&b0[o * 8];
        *(float4*)&bv[4]  = *(const float4*)&b0[o * 8 + 4];
        PK4 q[6];
        #pragma unroll
        for (int hp = 0; hp < 4; ++hp) {       // j-pairs, packed math
            const v2f wx = {wxv[2*hp], wxv[2*hp+1]};
            const v2f wy = {wyv[2*hp], wyv[2*hp+1]};
            const v2f bb = {bv[2*hp],  bv[2*hp+1]};
            v2f g1, g2;
            const v2f a = tanh_d2_p(x * wx + y * wy + bb, g1, g2);
            const v2f gx = g2 * wx;
            const v2f r0 = a,        r1 = g1 * wx,  r2 = g1 * wy;
            const v2f r3 = gx * wx,  r4 = gx * wy,  r5 = (g2 * wy) * wy;
            q[0].h[hp] = __builtin_amdgcn_cvt_pkrtz(r0.x, r0.y);
            q[1].h[hp] = __builtin_amdgcn_cvt_pkrtz(r1.x, r1.y);
            q[2].h[hp] = __builtin_amdgcn_cvt_pkrtz(r2.x, r2.y);
            q[3].h[hp] = __builtin_amdgcn_cvt_pkrtz(r3.x, r3.y);
            q[4].h[hp] = __builtin_amdgcn_cvt_pkrtz(r4.x, r4.y);
            q[5].h[hp] = __builtin_amdgcn_cvt_pkrtz(r5.x, r5.y);
        }
        #pragma unroll
        for (int pl = 0; pl < 6; ++pl)
            *(uint4*)&sSg[soct(pl, p, o)] = q[pl].u;
    };

    auto GEMM = [&](int layer) {
        const v8h* __restrict__ Ag = (const v8h*)(Wt + layer * (16 * H * 8));
        #pragma unroll
        for (int pl = 0; pl < 6; ++pl) { C[pl][0] = (v4f){0,0,0,0}; C[pl][1] = (v4f){0,0,0,0}; }
        v8h Aa0 = Ag[aoff];
        v8h Aa1 = Ag[aoff + 16];
        v8h Ab0 = Ag[aoff + 4 * H];
        v8h Ab1 = Ag[aoff + 4 * H + 16];
        auto kstep = [&](const v8h A0, const v8h A1, const int kc) {
            const int oct = kc * 4 + quad;
            #pragma unroll
            for (int pl = 0; pl < 6; ++pl) {
                const v8h B = *(const v8h*)&sSg[soct(pl, pmy, oct)];
                C[pl][0] = __builtin_amdgcn_mfma_f32_16x16x32_f16(A0, B, C[pl][0], 0, 0, 0);
                C[pl][1] = __builtin_amdgcn_mfma_f32_16x16x32_f16(A1, B, C[pl][1], 0, 0, 0);
            }
        };
        // name-rotated 1-ahead prefetch; fences bound in-flight A regs
        kstep(Aa0, Aa1, 0);
        __builtin_amdgcn_sched_barrier(0);
        Aa0 = Ag[aoff + 8 * H];
        Aa1 = Ag[aoff + 8 * H + 16];
        kstep(Ab0, Ab1, 1);
        __builtin_amdgcn_sched_barrier(0);
        Ab0 = Ag[aoff + 12 * H];
        Ab1 = Ag[aoff + 12 * H + 16];
        kstep(Aa0, Aa1, 2);
        __builtin_amdgcn_sched_barrier(0);
        kstep(Ab0, Ab1, 3);
    };

    auto E1 = [&]() {
        // packed in-register tanh chain rule; b64 vector writeback
        #pragma unroll
        for (int mt = 0; mt < 2; ++mt) {
            const int j0 = jquad * 32 + mt * 16 + quad * 4;
            const float4 bv = *(const float4*)&b1[j0];
            PK2 q[6];
            #pragma unroll
            for (int hp = 0; hp < 2; ++hp) {   // r-pairs (0,1) and (2,3)
                const v2f zb = hp ? (v2f){C[0][mt][2], C[0][mt][3]}
                                  : (v2f){C[0][mt][0], C[0][mt][1]};
                const v2f bb = hp ? (v2f){bv.z, bv.w} : (v2f){bv.x, bv.y};
                const v2f tx = hp ? (v2f){C[1][mt][2], C[1][mt][3]}
                                  : (v2f){C[1][mt][0], C[1][mt][1]};
                const v2f ty = hp ? (v2f){C[2][mt][2], C[2][mt][3]}
                                  : (v2f){C[2][mt][0], C[2][mt][1]};
                const v2f cx = hp ? (v2f){C[3][mt][2], C[3][mt][3]}
                                  : (v2f){C[3][mt][0], C[3][mt][1]};
                const v2f cm = hp ? (v2f){C[4][mt][2], C[4][mt][3]}
                                  : (v2f){C[4][mt][0], C[4][mt][1]};
                const v2f cy = hp ? (v2f){C[5][mt][2], C[5][mt][3]}
                                  : (v2f){C[5][mt][0], C[5][mt][1]};
                v2f g1, g2;
                const v2f a  = tanh_d2_p(zb + bb, g1, g2);
                const v2f gx = g2 * tx;
                const v2f s0 = a,        s1 = g1 * tx,          s2 = g1 * ty;
                const v2f s3 = gx * tx + g1 * cx;
                const v2f s4 = gx * ty + g1 * cm;
                const v2f s5 = (g2 * ty) * ty + g1 * cy;
                q[0].h[hp] = __builtin_amdgcn_cvt_pkrtz(s0.x, s0.y);
                q[1].h[hp] = __builtin_amdgcn_cvt_pkrtz(s1.x, s1.y);
                q[2].h[hp] = __builtin_amdgcn_cvt_pkrtz(s2.x, s2.y);
                q[3].h[hp] = __builtin_amdgcn_cvt_pkrtz(s3.x, s3.y);
                q[4].h[hp] = __builtin_amdgcn_cvt_pkrtz(s4.x, s4.y);
                q[5].h[hp] = __builtin_amdgcn_cvt_pkrtz(s5.x, s5.y);
            }
            const int ob = j0 >> 3;            // octet of j0
            const int ho = (quad & 1) * 4;     // half-offset within octet
            #pragma unroll
            for (int pl = 0; pl < 6; ++pl)
                *(uint2*)&sSg[soct(pl, pmy, ob) + ho] = q[pl].u;
        }
    };

    auto E2a = [&]() {
        // final combine + W3 dot, packed; reduce j over quads; write partials
        v2f axx = {0.f, 0.f}, axy = {0.f, 0.f}, ayy = {0.f, 0.f};
        #pragma unroll
        for (int mt = 0; mt < 2; ++mt) {
            const int j0 = jquad * 32 + mt * 16 + quad * 4;
            const float4 bv = *(const float4*)&b2[j0];
            const float4 wv = *(const float4*)&W3[j0];
            #pragma unroll
            for (int hp = 0; hp < 2; ++hp) {
                const v2f zb = hp ? (v2f){C[0][mt][2], C[0][mt][3]}
                                  : (v2f){C[0][mt][0], C[0][mt][1]};
                const v2f bb = hp ? (v2f){bv.z, bv.w} : (v2f){bv.x, bv.y};
                const v2f w3 = hp ? (v2f){wv.z, wv.w} : (v2f){wv.x, wv.y};
                const v2f tx = hp ? (v2f){C[1][mt][2], C[1][mt][3]}
                                  : (v2f){C[1][mt][0], C[1][mt][1]};
                const v2f ty = hp ? (v2f){C[2][mt][2], C[2][mt][3]}
                                  : (v2f){C[2][mt][0], C[2][mt][1]};
                const v2f cx = hp ? (v2f){C[3][mt][2], C[3][mt][3]}
                                  : (v2f){C[3][mt][0], C[3][mt][1]};
                const v2f cm = hp ? (v2f){C[4][mt][2], C[4][mt][3]}
                                  : (v2f){C[4][mt][0], C[4][mt][1]};
                const v2f cy = hp ? (v2f){C[5][mt][2], C[5][mt][3]}
                                  : (v2f){C[5][mt][0], C[5][mt][1]};
                v2f g1, g2;
                tanh_d2_p(zb + bb, g1, g2);
                const v2f gx = g2 * tx;
                axx = axx + w3 * (gx * tx + g1 * cx);
                axy = axy + w3 * (gx * ty + g1 * cm);
                ayy = ayy + w3 * ((g2 * ty) * ty + g1 * cy);
            }
        }
        float oxx = axx.x + axx.y, oxy = axy.x + axy.y, oyy = ayy.x + ayy.y;
        // reduce over quads (same p, disjoint j): 2-step butterfly
        oxx += __shfl_xor(oxx, 16); oxx += __shfl_xor(oxx, 32);
        oxy += __shfl_xor(oxy, 16); oxy += __shfl_xor(oxy, 32);
        oyy += __shfl_xor(oyy, 16); oyy += __shfl_xor(oyy, 32);
        // cross-wave (jquad) partials: overlay scratch on this group's sS
        // (all reads of sSg finished at the barrier after this group's G2)
        float* sRed = (float*)sSg;             // [3][4 jquad][16 p] = 768 B
        if (quad == 0) {
            sRed[0 * 64 + jquad * 16 + pmy] = oxx;
            sRed[1 * 64 + jquad * 16 + pmy] = oxy;
            sRed[2 * 64 + jquad * 16 + pmy] = oyy;
        }
    };

    auto E2b = [&]() {
        float* sRed = (float*)sSg;
        if (tl < 48) {
            const int c = tl >> 4, p = tl & 15;
            float acc = 0.f;
            #pragma unroll
            for (int jq = 0; jq < 4; ++jq)
                acc += sRed[c * 64 + jq * 16 + p];
            out[c * N + pbase + p] = acc;
        }
    };

    // ---------------- staggered window schedule ----------------
    if (grp == 0) L0();
    __syncthreads();                       // W0 -> W1
    if (grp == 0) GEMM(0); else L0();
    __syncthreads();                       // W1 -> W2
    if (grp == 0) E1();    else GEMM(0);
    __syncthreads();                       // W2 -> W3
    if (grp == 0) GEMM(1); else E1();
    __syncthreads();                       // W3 -> W4
    if (grp == 0) E2a();   else GEMM(1);
    __syncthreads();                       // W4 -> W5
    if (grp == 0) E2b();   else E2a();
    __syncthreads();                       // W5 -> W6
    if (grp == 1) E2b();
}

extern "C" void kernel_launch(void* const* d_in, const int* in_sizes, int n_in,
                              void* d_out, int out_size, void* d_ws, size_t ws_size,
                              hipStream_t stream) {
    const float* X  = (const float*)d_in[0];
    const float* W0 = (const float*)d_in[1];
    const float* b0 = (const float*)d_in[2];
    const float* W1 = (const float*)d_in[3];
    const float* b1 = (const float*)d_in[4];
    const float* W2 = (const float*)d_in[5];
    const float* b2 = (const float*)d_in[6];
    const float* W3 = (const float*)d_in[7];
    // d_in[8] = b3: constant offset, zero second derivative -> unused.

    const int N = in_sizes[0] / 2;               // 131072 = 4096 * 2P
    float* out = (float*)d_out;
    _Float16* ws = (_Float16*)d_ws;              // Wt[2][16][128][8] f16 = 64 KB

    hipLaunchKernelGGL(wt_convert, dim3(256), dim3(64), 0, stream, W1, W2, ws);

    hipLaunchKernelGGL(pinn_hess_mfma, dim3(N / (2 * P)), dim3(NT), 0, stream,
                       X, W0, b0, ws, b1, b2, W3, out, N);
}

// Round 5
// 136.612 us; speedup vs baseline: 1.0210x; 1.0210x over previous
//
#include <hip/hip_runtime.h>

#define H   128
#define P   16             // points per block (= MFMA N)
#define NT  512            // 8 waves: wave = jquad (16 j-rows each)

typedef _Float16 v8h __attribute__((ext_vector_type(8)));
typedef __fp16   h2  __attribute__((ext_vector_type(2)));   // cvt_pkrtz return type
typedef float    v4f __attribute__((ext_vector_type(4)));
typedef float    v2f __attribute__((ext_vector_type(2)));   // -> VOP3P v_pk_*_f32

union PK2 { h2 h[2]; uint2 u; };       // 4 f16 = 8 B

// State plane layout: [pl][p][k], 128 f16 per row, XOR-octet swizzle; returns
// f16 index of octet o of row p. (p&15 == p at P=16.)
__device__ __forceinline__ int soct(int pl, int p, int o) {
    return ((pl * P + p) * 16 + (o ^ (p & 15))) << 3;
}

// Prepass (free): Wt in MFMA A-fragment physical order ws[l][oct][j][8],
// oct = k>>3. Main kernel loads A fragments directly from this buffer into
// registers (64 KB, L2-resident) — A never touches LDS.
__global__ void wt_convert(const float* __restrict__ W1,
                           const float* __restrict__ W2,
                           _Float16* __restrict__ ws) {
    const int t = blockIdx.x * 64 + threadIdx.x;   // 0..16383 (u32 units)
    const int l = t >> 13;
    const int r = t & 8191;
    const int oct = r >> 9;
    const int rem = r & 511;
    const int j  = rem >> 2;
    const int wp = rem & 3;
    const int k  = oct * 8 + 2 * wp;
    const float* __restrict__ W = l ? W2 : W1;
    const float a = W[k * H + j];
    const float b = W[(k + 1) * H + j];
    union { h2 h; unsigned u; } q;
    q.h = __builtin_amdgcn_cvt_pkrtz(a, b);
    ((unsigned*)ws)[t] = q.u;
}

// Packed-pair tanh + derivatives: exp/rcp scalar, fma chain packed (VOP3P).
__device__ __forceinline__ v2f tanh_d2_p(v2f z, v2f& g1, v2f& g2) {
    v2f r;
    r.x = __builtin_amdgcn_rcpf(__expf(2.f * z.x) + 1.f);
    r.y = __builtin_amdgcn_rcpf(__expf(2.f * z.y) + 1.f);
    const v2f a = -2.f * r + 1.f;                  // e=inf -> r=0 -> a=1
    g1 = 1.f - a * a;
    g2 = -2.f * (a * g1);
    return a;
}

// R23: occupancy attack. Evidence from R17/R21/R22: dur pinned at 72-82us
// across 3 structures; VALUBusy ~47-51% top counter; Occupancy ~38% = 3
// waves/SIMD; tanh chain rule = serial dep chain -> VALU is stall-bound, not
// throughput-bound. Lever: 8 waves/SIMD, blocked by C=48 VGPR (128-tier).
// Fix: 8 waves x 16 j-rows per 16-pt tile -> C[6] = 24 VGPRs; A loaded
// per-kstep (no prefetch; 8-wave TLP hides L2 ~200cy instead of regs).
// GEMM live set ~60 <= 64 -> (512,8) = 8 waves/SIMD, 4 blocks/CU, 96KB LDS.
// Tripwire: VGPR=64 + WRITE_SIZE >> MB means spill -> revert to R17.
__global__ __launch_bounds__(NT, 8)
void pinn_hess_mfma(const float* __restrict__ X,
                    const float* __restrict__ W0, const float* __restrict__ b0,
                    const _Float16* __restrict__ Wt,
                    const float* __restrict__ b1, const float* __restrict__ b2,
                    const float* __restrict__ W3,
                    float* __restrict__ out, int N)
{
    __shared__ _Float16 sS[6 * P * H];        // 24576 B, swizzled state planes

    const int tid   = threadIdx.x;
    const int jquad = tid >> 6;               // wave 0..7 = j range /16
    const int lane  = tid & 63;
    const int quad  = lane >> 4;
    const int l15   = lane & 15;
    const int pbase = blockIdx.x * P;
    const int pmy   = l15;                    // this lane's point row (GEMM n)

    // ---------------- layer 0 (input dim 2, analytic); 512 tasks = 1/thread --
    // task = (point p, j-quad q4): 4 j-values, one uint2 write per plane.
    {
        const int p = tid >> 5, q4 = tid & 31;
        const float x = X[2 * (pbase + p)];
        const float y = X[2 * (pbase + p) + 1];
        const float4 wx4 = *(const float4*)&W0[q4 * 4];
        const float4 wy4 = *(const float4*)&W0[H + q4 * 4];
        const float4 bb4 = *(const float4*)&b0[q4 * 4];
        PK2 q[6];
        #pragma unroll
        for (int hp = 0; hp < 2; ++hp) {       // j-pairs, packed math
            const v2f wx = hp ? (v2f){wx4.z, wx4.w} : (v2f){wx4.x, wx4.y};
            const v2f wy = hp ? (v2f){wy4.z, wy4.w} : (v2f){wy4.x, wy4.y};
            const v2f bb = hp ? (v2f){bb4.z, bb4.w} : (v2f){bb4.x, bb4.y};
            v2f g1, g2;
            const v2f a = tanh_d2_p(x * wx + y * wy + bb, g1, g2);
            const v2f gx = g2 * wx;
            const v2f r0 = a,        r1 = g1 * wx,  r2 = g1 * wy;
            const v2f r3 = gx * wx,  r4 = gx * wy,  r5 = (g2 * wy) * wy;
            q[0].h[hp] = __builtin_amdgcn_cvt_pkrtz(r0.x, r0.y);
            q[1].h[hp] = __builtin_amdgcn_cvt_pkrtz(r1.x, r1.y);
            q[2].h[hp] = __builtin_amdgcn_cvt_pkrtz(r2.x, r2.y);
            q[3].h[hp] = __builtin_amdgcn_cvt_pkrtz(r3.x, r3.y);
            q[4].h[hp] = __builtin_amdgcn_cvt_pkrtz(r4.x, r4.y);
            q[5].h[hp] = __builtin_amdgcn_cvt_pkrtz(r5.x, r5.y);
        }
        const int o  = q4 >> 1;                // octet
        const int ho = (q4 & 1) * 4;           // half-offset within octet
        #pragma unroll
        for (int pl = 0; pl < 6; ++pl)
            *(uint2*)&sS[soct(pl, p, o) + ho] = q[pl].u;
    }

    // A-fragment index (v8h units) for this lane: [oct = kc*4+quad][j][8]
    const int aoff = quad * H + jquad * 16 + l15;   // + kc*4*H

    // ---------------- hidden layers ----------------
    for (int layer = 0; layer < 2; ++layer) {
        const v8h* __restrict__ Ag = (const v8h*)(Wt + layer * (16 * H * 8));

        __syncthreads();   // (1)/(3): sS writes visible

        v4f C[6];
        #pragma unroll
        for (int pl = 0; pl < 6; ++pl) C[pl] = (v4f){0, 0, 0, 0};

        #pragma unroll
        for (int kc = 0; kc < 4; ++kc) {
            const v8h A = Ag[aoff + kc * 4 * H];     // L2 hit; TLP hides latency
            const int oct = kc * 4 + quad;
            #pragma unroll
            for (int pl = 0; pl < 6; ++pl) {
                const v8h B = *(const v8h*)&sS[soct(pl, pmy, oct)];
                C[pl] = __builtin_amdgcn_mfma_f32_16x16x32_f16(A, B, C[pl], 0, 0, 0);
            }
        }

        __syncthreads();   // (2)/(4): all K-loop reads of sS done

        const int j0 = jquad * 16 + quad * 4;        // this lane's 4 j-rows

        if (layer == 0) {
            // packed in-register tanh chain rule; b64 vector writeback
            const float4 bv = *(const float4*)&b1[j0];
            PK2 q[6];
            #pragma unroll
            for (int hp = 0; hp < 2; ++hp) {   // r-pairs (0,1) and (2,3)
                const v2f zb = hp ? (v2f){C[0][2], C[0][3]} : (v2f){C[0][0], C[0][1]};
                const v2f bb = hp ? (v2f){bv.z, bv.w}       : (v2f){bv.x, bv.y};
                const v2f tx = hp ? (v2f){C[1][2], C[1][3]} : (v2f){C[1][0], C[1][1]};
                const v2f ty = hp ? (v2f){C[2][2], C[2][3]} : (v2f){C[2][0], C[2][1]};
                const v2f cx = hp ? (v2f){C[3][2], C[3][3]} : (v2f){C[3][0], C[3][1]};
                const v2f cm = hp ? (v2f){C[4][2], C[4][3]} : (v2f){C[4][0], C[4][1]};
                const v2f cy = hp ? (v2f){C[5][2], C[5][3]} : (v2f){C[5][0], C[5][1]};
                v2f g1, g2;
                const v2f a  = tanh_d2_p(zb + bb, g1, g2);
                const v2f gx = g2 * tx;
                const v2f s0 = a,        s1 = g1 * tx,          s2 = g1 * ty;
                const v2f s3 = gx * tx + g1 * cx;
                const v2f s4 = gx * ty + g1 * cm;
                const v2f s5 = (g2 * ty) * ty + g1 * cy;
                q[0].h[hp] = __builtin_amdgcn_cvt_pkrtz(s0.x, s0.y);
                q[1].h[hp] = __builtin_amdgcn_cvt_pkrtz(s1.x, s1.y);
                q[2].h[hp] = __builtin_amdgcn_cvt_pkrtz(s2.x, s2.y);
                q[3].h[hp] = __builtin_amdgcn_cvt_pkrtz(s3.x, s3.y);
                q[4].h[hp] = __builtin_amdgcn_cvt_pkrtz(s4.x, s4.y);
                q[5].h[hp] = __builtin_amdgcn_cvt_pkrtz(s5.x, s5.y);
            }
            const int ob = j0 >> 3;            // octet of j0
            const int ho = (quad & 1) * 4;     // half-offset within octet
            #pragma unroll
            for (int pl = 0; pl < 6; ++pl)
                *(uint2*)&sS[soct(pl, pmy, ob) + ho] = q[pl].u;
        } else {
            // final combine + W3 dot, packed; reduce j over quads then jquads
            v2f axx = {0.f, 0.f}, axy = {0.f, 0.f}, ayy = {0.f, 0.f};
            const float4 bv = *(const float4*)&b2[j0];
            const float4 wv = *(const float4*)&W3[j0];
            #pragma unroll
            for (int hp = 0; hp < 2; ++hp) {
                const v2f zb = hp ? (v2f){C[0][2], C[0][3]} : (v2f){C[0][0], C[0][1]};
                const v2f bb = hp ? (v2f){bv.z, bv.w}       : (v2f){bv.x, bv.y};
                const v2f w3 = hp ? (v2f){wv.z, wv.w}       : (v2f){wv.x, wv.y};
                const v2f tx = hp ? (v2f){C[1][2], C[1][3]} : (v2f){C[1][0], C[1][1]};
                const v2f ty = hp ? (v2f){C[2][2], C[2][3]} : (v2f){C[2][0], C[2][1]};
                const v2f cx = hp ? (v2f){C[3][2], C[3][3]} : (v2f){C[3][0], C[3][1]};
                const v2f cm = hp ? (v2f){C[4][2], C[4][3]} : (v2f){C[4][0], C[4][1]};
                const v2f cy = hp ? (v2f){C[5][2], C[5][3]} : (v2f){C[5][0], C[5][1]};
                v2f g1, g2;
                tanh_d2_p(zb + bb, g1, g2);
                const v2f gx = g2 * tx;
                axx = axx + w3 * (gx * tx + g1 * cx);
                axy = axy + w3 * (gx * ty + g1 * cm);
                ayy = ayy + w3 * ((g2 * ty) * ty + g1 * cy);
            }
            float oxx = axx.x + axx.y, oxy = axy.x + axy.y, oyy = ayy.x + ayy.y;
            // reduce over quads (same p, disjoint j): 2-step butterfly
            oxx += __shfl_xor(oxx, 16); oxx += __shfl_xor(oxx, 32);
            oxy += __shfl_xor(oxy, 16); oxy += __shfl_xor(oxy, 32);
            oyy += __shfl_xor(oyy, 16); oyy += __shfl_xor(oyy, 32);
            // cross-wave (jquad) partials: overlay scratch on sS (all reads
            // of sS finished at barrier (4) above)
            float* sRed = (float*)sS;              // [3][8 jquad][16 p] = 1.5 KB
            if (quad == 0) {
                sRed[0 * 128 + jquad * 16 + pmy] = oxx;
                sRed[1 * 128 + jquad * 16 + pmy] = oxy;
                sRed[2 * 128 + jquad * 16 + pmy] = oyy;
            }
            __syncthreads();   // (5) partials visible
            if (tid < 48) {
                const int c = tid >> 4, p = tid & 15;
                float acc = 0.f;
                #pragma unroll
                for (int jq = 0; jq < 8; ++jq)
                    acc += sRed[c * 128 + jq * 16 + p];
                out[c * N + pbase + p] = acc;
            }
        }
    }
}

extern "C" void kernel_launch(void* const* d_in, const int* in_sizes, int n_in,
                              void* d_out, int out_size, void* d_ws, size_t ws_size,
                              hipStream_t stream) {
    const float* X  = (const float*)d_in[0];
    const float* W0 = (const float*)d_in[1];
    const float* b0 = (const float*)d_in[2];
    const float* W1 = (const float*)d_in[3];
    const float* b1 = (const float*)d_in[4];
    const float* W2 = (const float*)d_in[5];
    const float* b2 = (const float*)d_in[6];
    const float* W3 = (const float*)d_in[7];
    // d_in[8] = b3: constant offset, zero second derivative -> unused.

    const int N = in_sizes[0] / 2;               // 131072 = 8192 * P
    float* out = (float*)d_out;
    _Float16* ws = (_Float16*)d_ws;              // Wt[2][16][128][8] f16 = 64 KB

    hipLaunchKernelGGL(wt_convert, dim3(256), dim3(64), 0, stream, W1, W2, ws);

    hipLaunchKernelGGL(pinn_hess_mfma, dim3(N / P), dim3(NT), 0, stream,
                       X, W0, b0, ws, b1, b2, W3, out, N);
}